// Round 3
// baseline (163.766 us; speedup 1.0000x reference)
//
#include <hip/hip_runtime.h>

#define BS      128
#define NF      4
#define NC      36
#define P_LO    1024
#define P_HI    16384
#define KNN     9
#define THREADS 256
#define TILE_P  256
#define NTILES  (P_HI / TILE_P)     // 64
#define LIST_OFF 64                 // ints; ws[0..35]=counts, ws[64+c*128+i]=sample ids
#define SCHED_OFF 36                // 9 ints = 36 packed bytes: rank -> class (LPT order)

#define WBUF_BYTES (TILE_P * KNN * 4)   // 9216
#define YBUF_BYTES (P_LO * 16)          // 16384

// ---- pre-pass: bucket samples by class; also LPT schedule (count desc) ----
__global__ __launch_bounds__(128) void build_lists_kernel(
    const int* __restrict__ cls_ids, int* __restrict__ ws)
{
    __shared__ int cnt[NC];
    __shared__ int pk[9];
    const int t = threadIdx.x;
    if (t < NC) cnt[t] = 0;
    if (t >= 64 && t < 73) pk[t - 64] = 0;
    __syncthreads();
    if (t < BS) {
        int c = cls_ids[t];
        int pos = atomicAdd(&cnt[c], 1);
        ws[LIST_OFF + c * BS + pos] = t;
    }
    __syncthreads();
    if (t < NC) {
        int ct = cnt[t];
        ws[t] = ct;
        int r = 0;                       // rank by (count desc, idx asc) -> bijective
        for (int j = 0; j < NC; ++j) {
            int cj = cnt[j];
            r += (cj > ct) || (cj == ct && j < t);
        }
        atomicOr(&pk[r >> 2], t << ((r & 3) << 3));
    }
    __syncthreads();
    if (t < 9) ws[SCHED_OFF + t] = pk[t];
}

__device__ __forceinline__ void async_cp16(const void* g, void* l) {
    __builtin_amdgcn_global_load_lds(
        (const __attribute__((address_space(1))) void*)g,
        (__attribute__((address_space(3))) void*)l, 16, 0, 0);
}

// ---- main: block = (cls, tile); loops f=0..3; 4 samples/round ----
// NOTE: plain __launch_bounds__(256) — a (256,8) floor previously forced
// VGPR=32 and spilled (+126 MB HBM writes). LDS 25600 B caps at 6 blocks/CU.
__global__ __launch_bounds__(THREADS) void rect_up_kernel(
    const float* __restrict__ x,       // (BS, NF*P_LO)
    const int*   __restrict__ ws,      // counts + schedule + lists
    const int*   __restrict__ nbr,     // (P_HI, K)
    const float* __restrict__ wmap,    // (NC, NF, P_HI, K)
    const float* __restrict__ blo,     // (NC, NF, P_LO)
    const float* __restrict__ bhi,     // (NC, NF, P_HI)
    float*       __restrict__ out)     // (BS, NF, P_HI)
{
    __shared__ __align__(16) char smem[WBUF_BYTES + YBUF_BYTES];   // 25600 B

    const int tile = blockIdx.x & (NTILES - 1);
    const int g    = blockIdx.x >> 6;                    // schedule rank
    const int cls  = (ws[SCHED_OFF + (g >> 2)] >> ((g & 3) << 3)) & 0xFF;

    const int n_b = ws[cls];
    if (n_b == 0) return;              // uniform exit, before any __syncthreads

    const int tid   = threadIdx.x;
    const int tbase = tile * TILE_P;
    const int p     = tbase + tid;     // this thread's hi position

    float4* wbuf  = (float4*)smem;                        // 576 f4
    float4* ybuf4 = (float4*)(smem + WBUF_BYTES);         // 1024 f4
    float4* idst  = ybuf4;             // idx stage overlays ybuf; dead before 1st write

    // ---- async-stage w(f=0) tile and idx tile into LDS ----
    {
        const float4* wsrc = (const float4*)(wmap + ((size_t)(cls * NF + 0) * P_HI + tbase) * KNN);
        const float4* isrc = (const float4*)(nbr + (size_t)tbase * KNN);
        async_cp16(wsrc + tid,       wbuf + tid);
        async_cp16(wsrc + tid + 256, wbuf + tid + 256);
        async_cp16(isrc + tid,       idst + tid);
        async_cp16(isrc + tid + 256, idst + tid + 256);
        if (tid < 64) {                // wave-aligned tail (576-512 = 64 = 1 wave)
            async_cp16(wsrc + 512 + tid, wbuf + 512 + tid);
            async_cp16(isrc + 512 + tid, idst + 512 + tid);
        }
    }

    const int* list = ws + LIST_OFF + cls * BS;
    const int bid0 = list[0];
    const int bid1 = (1 < n_b) ? list[1] : bid0;
    const int bid2 = (2 < n_b) ? list[2] : bid0;
    const int bid3 = (3 < n_b) ? list[3] : bid0;

    // prefetch round-0 x values for f=0 (hides under the stage wait)
    float xv[16];                      // xv[m*4+s]: position q=tid+m*256, sample s
    {
        const float* x0 = x + ((size_t)(bid0 * NF + 0)) * P_LO;
        const float* x1 = x + ((size_t)(bid1 * NF + 0)) * P_LO;
        const float* x2 = x + ((size_t)(bid2 * NF + 0)) * P_LO;
        const float* x3 = x + ((size_t)(bid3 * NF + 0)) * P_LO;
        #pragma unroll
        for (int m = 0; m < 4; ++m) {
            const int q = tid + (m << 8);
            xv[m * 4 + 0] = x0[q];
            xv[m * 4 + 1] = x1[q];
            xv[m * 4 + 2] = x2[q];
            xv[m * 4 + 3] = x3[q];
        }
    }

    asm volatile("s_waitcnt vmcnt(0)" ::: "memory");
    __syncthreads();

    // ---- idx readback ONCE (stride-9 words: 2 lanes/bank = free) ----
    int nb[KNN];
    {
        const int* irow = (const int*)(smem + WBUF_BYTES) + (size_t)tid * KNN;
        #pragma unroll
        for (int k = 0; k < KNN; ++k) nb[k] = irow[k];
    }

    const int R = (n_b + 3) >> 2;      // rounds of 4 samples

    for (int f = 0; f < NF; ++f) {
        // per-f biases (global loads overlap the w readback below)
        float blv[4];
        {
            const float* blp = blo + (size_t)(cls * NF + f) * P_LO;
            #pragma unroll
            for (int m = 0; m < 4; ++m) blv[m] = blp[tid + (m << 8)];
        }
        const float bh = bhi[(size_t)(cls * NF + f) * P_HI + p];

        // w_f readback from wbuf
        float w[KNN];
        {
            const float* wrow = (const float*)smem + (size_t)tid * KNN;
            #pragma unroll
            for (int k = 0; k < KNN; ++k) w[k] = wrow[k];
        }
        __syncthreads();               // wbuf (and idst at f=0) free

        for (int r = 0; r < R; ++r) {
            int c0, c1, c2, c3;
            if (r == 0) {
                c0 = bid0; c1 = bid1; c2 = bid2; c3 = bid3;
                #pragma unroll
                for (int m = 0; m < 4; ++m) {
                    float4 v;
                    v.x = xv[m * 4 + 0] - blv[m];
                    v.y = xv[m * 4 + 1] - blv[m];
                    v.z = xv[m * 4 + 2] - blv[m];
                    v.w = xv[m * 4 + 3] - blv[m];
                    ybuf4[tid + (m << 8)] = v;
                }
            } else {                   // rare (R>1): inline-load path
                const int s0 = 4 * r;
                c0 = list[s0];
                c1 = (s0 + 1 < n_b) ? list[s0 + 1] : c0;
                c2 = (s0 + 2 < n_b) ? list[s0 + 2] : c0;
                c3 = (s0 + 3 < n_b) ? list[s0 + 3] : c0;
                const float* x0 = x + ((size_t)(c0 * NF + f)) * P_LO;
                const float* x1 = x + ((size_t)(c1 * NF + f)) * P_LO;
                const float* x2 = x + ((size_t)(c2 * NF + f)) * P_LO;
                const float* x3 = x + ((size_t)(c3 * NF + f)) * P_LO;
                #pragma unroll
                for (int m = 0; m < 4; ++m) {
                    const int q = tid + (m << 8);
                    float4 v;
                    v.x = x0[q] - blv[m];
                    v.y = x1[q] - blv[m];
                    v.z = x2[q] - blv[m];
                    v.w = x3[q] - blv[m];
                    ybuf4[q] = v;
                }
            }
            __syncthreads();           // ybuf ready

            // Issue f+1 prefetches HERE (after the barrier, not before it —
            // __syncthreads drains vmcnt, so issuing earlier would expose the
            // DMA at the barrier). Latency hides under gather + handoff.
            if (r == 0 && f + 1 < NF) {
                const float4* wsrc = (const float4*)(wmap + ((size_t)(cls * NF + f + 1) * P_HI + tbase) * KNN);
                async_cp16(wsrc + tid,       wbuf + tid);
                async_cp16(wsrc + tid + 256, wbuf + tid + 256);
                if (tid < 64) async_cp16(wsrc + 512 + tid, wbuf + 512 + tid);
                const float* x0 = x + ((size_t)(bid0 * NF + f + 1)) * P_LO;
                const float* x1 = x + ((size_t)(bid1 * NF + f + 1)) * P_LO;
                const float* x2 = x + ((size_t)(bid2 * NF + f + 1)) * P_LO;
                const float* x3 = x + ((size_t)(bid3 * NF + f + 1)) * P_LO;
                #pragma unroll
                for (int m = 0; m < 4; ++m) {
                    const int q = tid + (m << 8);
                    xv[m * 4 + 0] = x0[q];
                    xv[m * 4 + 1] = x1[q];
                    xv[m * 4 + 2] = x2[q];
                    xv[m * 4 + 3] = x3[q];
                }
            }

            // gather: one ds_read_b128 per neighbor feeds 4 samples' FMAs
            float a0 = 0.f, a1 = 0.f, a2 = 0.f, a3 = 0.f;
            #pragma unroll
            for (int k = 0; k < KNN; ++k) {
                const float4 yv = ybuf4[nb[k]];
                a0 = fmaf(w[k], yv.x, a0);
                a1 = fmaf(w[k], yv.y, a1);
                a2 = fmaf(w[k], yv.z, a2);
                a3 = fmaf(w[k], yv.w, a3);
            }
            const int s0 = 4 * r;
            out[(size_t)(c0 * NF + f) * P_HI + p] = a0 + bh;
            if (s0 + 1 < n_b) out[(size_t)(c1 * NF + f) * P_HI + p] = a1 + bh;
            if (s0 + 2 < n_b) out[(size_t)(c2 * NF + f) * P_HI + p] = a2 + bh;
            if (s0 + 3 < n_b) out[(size_t)(c3 * NF + f) * P_HI + p] = a3 + bh;

            if (r + 1 < R) __syncthreads();   // protect ybuf rewrite next round
        }
        if (f + 1 < NF) __syncthreads();      // drains w-DMA + xv; gathers done
    }
}

extern "C" void kernel_launch(void* const* d_in, const int* in_sizes, int n_in,
                              void* d_out, int out_size, void* d_ws, size_t ws_size,
                              hipStream_t stream) {
    const float* x    = (const float*)d_in[0];
    const int*   cls  = (const int*)d_in[1];
    const int*   nbr  = (const int*)d_in[2];
    const float* wmap = (const float*)d_in[3];
    const float* blo  = (const float*)d_in[4];
    const float* bhi  = (const float*)d_in[5];
    float*       out  = (float*)d_out;
    int*         wsl  = (int*)d_ws;   // needs (64 + 36*128)*4 = 18.7 KB

    build_lists_kernel<<<1, 128, 0, stream>>>(cls, wsl);
    rect_up_kernel<<<NC * NTILES, THREADS, 0, stream>>>(
        x, wsl, nbr, wmap, blo, bhi, out);
}

// Round 4
// 159.424 us; speedup vs baseline: 1.0272x; 1.0272x over previous
//
#include <hip/hip_runtime.h>

#define BS      128
#define NF      4
#define NC      36
#define P_LO    1024
#define P_HI    16384
#define KNN     9
#define THREADS 256
#define TILE_P  256
#define NTILES  (P_HI / TILE_P)     // 64
#define LIST_OFF 64                 // ints; ws[0..35]=counts, ws[64+c*128+i]=sample ids
#define SCHED_OFF 36                // 9 ints = 36 packed bytes: rank -> class (LPT order)

// ---- pre-pass: bucket samples by class; also LPT schedule (count desc) ----
__global__ __launch_bounds__(128) void build_lists_kernel(
    const int* __restrict__ cls_ids, int* __restrict__ ws)
{
    __shared__ int cnt[NC];
    __shared__ int pk[9];
    const int t = threadIdx.x;
    if (t < NC) cnt[t] = 0;
    if (t >= 64 && t < 73) pk[t - 64] = 0;
    __syncthreads();
    if (t < BS) {
        int c = cls_ids[t];
        int pos = atomicAdd(&cnt[c], 1);
        ws[LIST_OFF + c * BS + pos] = t;
    }
    __syncthreads();
    if (t < NC) {
        int ct = cnt[t];
        ws[t] = ct;
        int r = 0;                       // rank by (count desc, idx asc) -> bijective
        for (int j = 0; j < NC; ++j) {
            int cj = cnt[j];
            r += (cj > ct) || (cj == ct && j < t);
        }
        atomicOr(&pk[r >> 2], t << ((r & 3) << 3));
    }
    __syncthreads();
    if (t < 9) ws[SCHED_OFF + t] = pk[t];
}

// LDS-only barrier: __syncthreads would drain vmcnt(0) (stores + prefetches).
// Correctness here only needs ds-op ordering -> wait lgkmcnt, raw s_barrier.
// "memory" clobber pins LDS ops on the correct side (guide rule #18 analog).
__device__ __forceinline__ void lds_barrier() {
    asm volatile("s_waitcnt lgkmcnt(0)" ::: "memory");
    __builtin_amdgcn_s_barrier();
}

// ---- main: block = (cls, f, tile); w/nb direct-to-reg; 4 samples/round ----
// No LDS staging of w/idx: per-thread rows are 9 contiguous words; a wave's
// scalar loads cover 2304 contiguous bytes (18 lines, fully used, L1-merged).
// Kills the DMA -> vmcnt(0) -> barrier -> readback -> barrier prologue chain.
__global__ __launch_bounds__(THREADS) void rect_up_kernel(
    const float* __restrict__ x,       // (BS, NF*P_LO)
    const int*   __restrict__ ws,      // counts + schedule + lists
    const int*   __restrict__ nbr,     // (P_HI, K)
    const float* __restrict__ wmap,    // (NC, NF, P_HI, K)
    const float* __restrict__ blo,     // (NC, NF, P_LO)
    const float* __restrict__ bhi,     // (NC, NF, P_HI)
    float*       __restrict__ out)     // (BS, NF, P_HI)
{
    __shared__ __align__(16) float4 ybuf4[P_LO];   // 16384 B: 4 samples interleaved
    __shared__ int ls[BS];                          // 512 B: this class's sample ids

    const int tile = blockIdx.x & (NTILES - 1);
    const int g    = blockIdx.x >> 6;               // (rank, f)
    const int f    = g & (NF - 1);
    const int rank = g >> 2;
    const int cls  = (ws[SCHED_OFF + (rank >> 2)] >> ((rank & 3) << 3)) & 0xFF;

    const int n_b = ws[cls];
    if (n_b == 0) return;              // uniform exit, before any barrier

    const int tid   = threadIdx.x;
    const int tbase = tile * TILE_P;
    const int p     = tbase + tid;     // this thread's hi position

    const int* list = ws + LIST_OFF + cls * BS;
    if (tid < n_b) ls[tid] = list[tid];             // LDS list cache (R>1 path)

    int c0 = list[0];
    int c1 = (1 < n_b) ? list[1] : c0;
    int c2 = (2 < n_b) ? list[2] : c0;
    int c3 = (3 < n_b) ? list[3] : c0;

    // one latency group of independent loads: w-row, nb-row, biases, x round 0
    float w[KNN]; int nb[KNN];
    {
        const float* wr = wmap + ((size_t)(cls * NF + f) * P_HI + p) * KNN;
        const int*   ir = nbr + (size_t)p * KNN;
        #pragma unroll
        for (int k = 0; k < KNN; ++k) { w[k] = wr[k]; nb[k] = ir[k]; }
    }
    float blv[4];
    {
        const float* blp = blo + (size_t)(cls * NF + f) * P_LO;
        #pragma unroll
        for (int m = 0; m < 4; ++m) blv[m] = blp[tid + (m << 8)];
    }
    const float bh = bhi[(size_t)(cls * NF + f) * P_HI + p];

    float xv[16];                      // xv[m*4+s]: position q=tid+m*256, sample s
    {
        const float* x0 = x + (size_t)(c0 * NF + f) * P_LO;
        const float* x1 = x + (size_t)(c1 * NF + f) * P_LO;
        const float* x2 = x + (size_t)(c2 * NF + f) * P_LO;
        const float* x3 = x + (size_t)(c3 * NF + f) * P_LO;
        #pragma unroll
        for (int m = 0; m < 4; ++m) {
            const int q = tid + (m << 8);
            xv[m * 4 + 0] = x0[q];
            xv[m * 4 + 1] = x1[q];
            xv[m * 4 + 2] = x2[q];
            xv[m * 4 + 3] = x3[q];
        }
    }

    const int R = (n_b + 3) >> 2;      // rounds of 4 samples

    for (int r = 0; r < R; ++r) {
        // stage 4 bias-subtracted planes, sample-interleaved (b128 writes)
        #pragma unroll
        for (int m = 0; m < 4; ++m) {
            const int q = tid + (m << 8);
            float4 v;
            v.x = xv[m * 4 + 0] - blv[m];
            v.y = xv[m * 4 + 1] - blv[m];
            v.z = xv[m * 4 + 2] - blv[m];
            v.w = xv[m * 4 + 3] - blv[m];
            ybuf4[q] = v;
        }
        lds_barrier();                 // ybuf (and ls at r=0) visible; stores ride

        const int s0 = 4 * r;
        const int d0 = c0, d1 = c1, d2 = c2, d3 = c3;   // this round's sample ids

        if (r + 1 < R) {               // prefetch next round under the gather
            const int s = s0 + 4;
            c0 = ls[s];
            c1 = (s + 1 < n_b) ? ls[s + 1] : c0;
            c2 = (s + 2 < n_b) ? ls[s + 2] : c0;
            c3 = (s + 3 < n_b) ? ls[s + 3] : c0;
            const float* x0 = x + (size_t)(c0 * NF + f) * P_LO;
            const float* x1 = x + (size_t)(c1 * NF + f) * P_LO;
            const float* x2 = x + (size_t)(c2 * NF + f) * P_LO;
            const float* x3 = x + (size_t)(c3 * NF + f) * P_LO;
            #pragma unroll
            for (int m = 0; m < 4; ++m) {
                const int q = tid + (m << 8);
                xv[m * 4 + 0] = x0[q];
                xv[m * 4 + 1] = x1[q];
                xv[m * 4 + 2] = x2[q];
                xv[m * 4 + 3] = x3[q];
            }
        }

        // gather: one ds_read_b128 per neighbor feeds 4 samples' FMAs
        float a0 = 0.f, a1 = 0.f, a2 = 0.f, a3 = 0.f;
        #pragma unroll
        for (int k = 0; k < KNN; ++k) {
            const float4 yv = ybuf4[nb[k]];
            a0 = fmaf(w[k], yv.x, a0);
            a1 = fmaf(w[k], yv.y, a1);
            a2 = fmaf(w[k], yv.z, a2);
            a3 = fmaf(w[k], yv.w, a3);
        }

        out[(size_t)(d0 * NF + f) * P_HI + p] = a0 + bh;
        if (s0 + 1 < n_b) out[(size_t)(d1 * NF + f) * P_HI + p] = a1 + bh;
        if (s0 + 2 < n_b) out[(size_t)(d2 * NF + f) * P_HI + p] = a2 + bh;
        if (s0 + 3 < n_b) out[(size_t)(d3 * NF + f) * P_HI + p] = a3 + bh;

        if (r + 1 < R) lds_barrier();  // gathers done before ybuf rewrite
    }
}

extern "C" void kernel_launch(void* const* d_in, const int* in_sizes, int n_in,
                              void* d_out, int out_size, void* d_ws, size_t ws_size,
                              hipStream_t stream) {
    const float* x    = (const float*)d_in[0];
    const int*   cls  = (const int*)d_in[1];
    const int*   nbr  = (const int*)d_in[2];
    const float* wmap = (const float*)d_in[3];
    const float* blo  = (const float*)d_in[4];
    const float* bhi  = (const float*)d_in[5];
    float*       out  = (float*)d_out;
    int*         wsl  = (int*)d_ws;   // needs (64 + 36*128)*4 = 18.7 KB

    build_lists_kernel<<<1, 128, 0, stream>>>(cls, wsl);
    rect_up_kernel<<<NC * NF * NTILES, THREADS, 0, stream>>>(
        x, wsl, nbr, wmap, blo, bhi, out);
}